// Round 3
// baseline (125.589 us; speedup 1.0000x reference)
//
#include <hip/hip_runtime.h>
#include <cmath>

#define BB 256
#define TT 16
#define SS 32
#define DD 768
#define LROW 260   // LDS staging row stride (floats), 16B-aligned

// ---------------------------------------------------------------------------
// stage1: per batch row i (256 blocks x 512 threads, flat: 1 block/CU)
//   sim[t][s] = ls*<vl[i,t,:], tl[i,s,:]>; tw = softmax_t(max_s sim)
//   vw[i,:] = sum_t tw[t]*vl[i,t,:];  tb[i,:] = mean_s tl[i,s,:]
// vs baseline: +register prefetch of next chunk under compute,
//              +tb folded into staging (kills the 25 MB tl re-read),
//              +out-zero folded into block 0 (kills the memset dispatch).
// ---------------------------------------------------------------------------
__global__ __launch_bounds__(512) void hl_stage1(
    const float* __restrict__ vl, const float* __restrict__ tl,
    const float* __restrict__ temp,
    float* __restrict__ vw_ws, float* __restrict__ tb_ws,
    float* __restrict__ out, int out_n)
{
    __shared__ float lds[15104];
    float* smem  = lds;            // [48][260] staging (vl rows 0-15, tl 16-47)
    float* tbacc = lds + 12480;    // [8][260] tb partials
    float* simb  = lds + 14560;    // [512]
    float* rmaxb = lds + 15072;    // [16]
    float* twb   = lds + 15088;    // [16]
    // transpose region [512][17] aliases smem (staging dead by then)

    const int i   = blockIdx.x;
    const int tid = threadIdx.x;
    const float lsc = expf(temp[0]);
    if (i == 0) {                  // replaces hipMemsetAsync dispatch
        for (int o = tid; o < out_n; o += 512) out[o] = 0.f;
    }

    const int slice = tid & 15;    // d sub-offset (16 lanes x 16B)
    const int g     = tid >> 4;
    const int tgr   = g >> 3;      // t rows tgr*4..+4
    const int sg    = g & 7;       // s rows sg*4..+4

    const int r0 = tid >> 6;       // 0..7   staging row base
    const int dc = (tid & 63) << 2;// 0..252 staging d-quad

    const float* vli = vl + (size_t)i * TT * DD;
    const float* tli = tl + (size_t)i * SS * DD;

    float acc[4][4];
#pragma unroll
    for (int a = 0; a < 4; ++a)
#pragma unroll
        for (int b = 0; b < 4; ++b) acc[a][b] = 0.f;

    float4 pv[2], pt[4];
    // preload chunk 0 into registers
    pv[0] = *(const float4*)&vli[(r0    ) * DD + dc];
    pv[1] = *(const float4*)&vli[(r0 + 8) * DD + dc];
#pragma unroll
    for (int k = 0; k < 4; ++k)
        pt[k] = *(const float4*)&tli[(r0 + 8 * k) * DD + dc];

    for (int c = 0; c < 3; ++c) {
        // publish chunk c from registers
        *(float4*)&smem[(r0    ) * LROW + dc] = pv[0];
        *(float4*)&smem[(r0 + 8) * LROW + dc] = pv[1];
#pragma unroll
        for (int k = 0; k < 4; ++k)
            *(float4*)&smem[(16 + r0 + 8 * k) * LROW + dc] = pt[k];
        {   // tb partial: sum of this thread's 4 s-rows for its d-quad
            float4 ps = {pt[0].x + pt[1].x + pt[2].x + pt[3].x,
                         pt[0].y + pt[1].y + pt[2].y + pt[3].y,
                         pt[0].z + pt[1].z + pt[2].z + pt[3].z,
                         pt[0].w + pt[1].w + pt[2].w + pt[3].w};
            *(float4*)&tbacc[r0 * LROW + dc] = ps;
        }
        __syncthreads();
        if (c < 2) {               // prefetch chunk c+1 under compute
            const int d0n = (c + 1) << 8;
            pv[0] = *(const float4*)&vli[(r0    ) * DD + d0n + dc];
            pv[1] = *(const float4*)&vli[(r0 + 8) * DD + d0n + dc];
#pragma unroll
            for (int k = 0; k < 4; ++k)
                pt[k] = *(const float4*)&tli[(r0 + 8 * k) * DD + d0n + dc];
        }
#pragma unroll
        for (int step = 0; step < 4; ++step) {
            const int db = (slice << 4) + (step << 2);
            float4 av[4], bv[4];
#pragma unroll
            for (int ti = 0; ti < 4; ++ti)
                av[ti] = *(const float4*)&smem[(tgr * 4 + ti) * LROW + db];
#pragma unroll
            for (int sj = 0; sj < 4; ++sj)
                bv[sj] = *(const float4*)&smem[(16 + sg * 4 + sj) * LROW + db];
#pragma unroll
            for (int ti = 0; ti < 4; ++ti)
#pragma unroll
                for (int sj = 0; sj < 4; ++sj)
                    acc[ti][sj] += av[ti].x * bv[sj].x + av[ti].y * bv[sj].y
                                 + av[ti].z * bv[sj].z + av[ti].w * bv[sj].w;
        }
        if (tid < 256) {           // finish tb for chunk c (tbacc via sync above)
            float s = 0.f;
#pragma unroll
            for (int j = 0; j < 8; ++j) s += tbacc[j * LROW + tid];
            tb_ws[(size_t)i * DD + (c << 8) + tid] = s * (1.0f / 32.0f);
        }
        __syncthreads();           // guards smem AND tbacc rewrite
    }

    // split-D transpose (alias staging region): [pair][slice], pad 17
#pragma unroll
    for (int ti = 0; ti < 4; ++ti)
#pragma unroll
        for (int sj = 0; sj < 4; ++sj) {
            int t = tgr * 4 + ti, s = sg * 4 + sj;
            smem[(t * 32 + s) * 17 + slice] = acc[ti][sj];
        }
    __syncthreads();
    {   // pair `tid` reduce over 16 slices
        float ssum = 0.f;
#pragma unroll
        for (int k = 0; k < 16; ++k) ssum += smem[tid * 17 + k];
        simb[tid] = lsc * ssum;
    }
    __syncthreads();
    if (tid < 16) {                // rowmax over s (rotated to avoid bank clash)
        float m = -3.0e38f;
        for (int s = 0; s < 32; ++s)
            m = fmaxf(m, simb[tid * 32 + ((s + tid) & 31)]);
        rmaxb[tid] = m;
    }
    __syncthreads();
    if (tid == 0) {                // tw = softmax over 16 t values
        float M = -3.0e38f;
        for (int t = 0; t < 16; ++t) M = fmaxf(M, rmaxb[t]);
        float ssum = 0.f;
        for (int t = 0; t < 16; ++t) {
            float e = expf(rmaxb[t] - M);
            twb[t] = e;
            ssum += e;
        }
        float inv = 1.0f / ssum;
        for (int t = 0; t < 16; ++t) twb[t] *= inv;
    }
    __syncthreads();

    // vw tail: coalesced, L2-hot re-read of vl only (tb already written)
    for (int d = tid; d < DD; d += 512) {
        float vwv = 0.f;
#pragma unroll
        for (int t = 0; t < 16; ++t) vwv += twb[t] * vli[t * DD + d];
        vw_ws[(size_t)i * DD + d] = vwv;
    }
}

// ---------------------------------------------------------------------------
// hl_gemm: 256 blocks = mat(2) x ti(4) x tj(4) x p(8 K-splits of 96)
//   flat: 1 job per block per CU (width > fusion, per rounds 0-2 lesson).
//   mat 0: G = ls*vg@tg^T -> cparts cm=1 (+ transpose into cm=2)
//   mat 1: L = ls*vw@tb^T -> cparts cm=0
// + register prefetch of next K-chunk under compute.
// ---------------------------------------------------------------------------
__global__ __launch_bounds__(256) void hl_gemm(
    const float* __restrict__ vg, const float* __restrict__ tg,
    const float* __restrict__ vw, const float* __restrict__ tb,
    const float* __restrict__ temp, float* __restrict__ cparts)
{
    __shared__ float As[16][68];
    __shared__ float Bs[16][68];
    __shared__ float Tb[64][68];

    const int b   = blockIdx.x;
    const int p   = b & 7;
    const int tj  = (b >> 3) & 3;
    const int ti  = (b >> 5) & 3;
    const int mat = b >> 7;
    const int tid = threadIdx.x;
    const float lsc = expf(temp[0]);

    const float* A  = mat ? vw : vg;
    const float* Bm = mat ? tb : tg;
    const int i0 = ti * 64, j0 = tj * 64, kb0 = p * 96;

    const int srow = tid >> 2, skq = tid & 3;   // staging: row, k-quad
    const int tr = tid >> 4, tc = tid & 15;     // compute: 4 rows, 4 cols each

    float acc[4][4];
#pragma unroll
    for (int r = 0; r < 4; ++r)
#pragma unroll
        for (int cc = 0; cc < 4; ++cc) acc[r][cc] = 0.f;

    float4 a4 = *(const float4*)&A [(size_t)(i0 + srow) * DD + kb0 + skq * 4];
    float4 b4 = *(const float4*)&Bm[(size_t)(j0 + srow) * DD + kb0 + skq * 4];
    float4 a4n = a4, b4n = b4;
    for (int ch = 0; ch < 6; ++ch) {
        __syncthreads();
        As[skq * 4 + 0][srow] = a4.x; As[skq * 4 + 1][srow] = a4.y;
        As[skq * 4 + 2][srow] = a4.z; As[skq * 4 + 3][srow] = a4.w;
        Bs[skq * 4 + 0][srow] = b4.x; Bs[skq * 4 + 1][srow] = b4.y;
        Bs[skq * 4 + 2][srow] = b4.z; Bs[skq * 4 + 3][srow] = b4.w;
        __syncthreads();
        if (ch < 5) {              // prefetch next K-chunk under compute
            const int kb = kb0 + (ch + 1) * 16;
            a4n = *(const float4*)&A [(size_t)(i0 + srow) * DD + kb + skq * 4];
            b4n = *(const float4*)&Bm[(size_t)(j0 + srow) * DD + kb + skq * 4];
        }
#pragma unroll
        for (int k = 0; k < 16; ++k) {
            float4 av = *(const float4*)&As[k][tr * 4];
            float4 bv = *(const float4*)&Bs[k][tc * 4];
            float ar[4] = {av.x, av.y, av.z, av.w};
            float br[4] = {bv.x, bv.y, bv.z, bv.w};
#pragma unroll
            for (int r = 0; r < 4; ++r)
#pragma unroll
                for (int cc = 0; cc < 4; ++cc)
                    acc[r][cc] += ar[r] * br[cc];
        }
        a4 = a4n; b4 = b4n;
    }

    const int cm = mat ? 0 : 1;
    float* Cp = cparts + ((size_t)p * 3 + cm) * 65536;
#pragma unroll
    for (int r = 0; r < 4; ++r) {
        float4 v = {acc[r][0] * lsc, acc[r][1] * lsc, acc[r][2] * lsc, acc[r][3] * lsc};
        *(float4*)&Cp[(size_t)(i0 + tr * 4 + r) * 256 + j0 + tc * 4] = v;
    }
    if (mat == 0) {   // also write G^T for the t2v column-LSE
        __syncthreads();
#pragma unroll
        for (int r = 0; r < 4; ++r)
#pragma unroll
            for (int cc = 0; cc < 4; ++cc)
                Tb[tc * 4 + cc][tr * 4 + r] = acc[r][cc] * lsc;
        __syncthreads();
        float* Ct = cparts + ((size_t)p * 3 + 2) * 65536;
#pragma unroll
        for (int r = 0; r < 4; ++r) {
            float4 v = *(const float4*)&Tb[tr * 4 + r][tc * 4];
            *(float4*)&Ct[(size_t)(j0 + tr * 4 + r) * 256 + i0 + tc * 4] = v;
        }
    }
}

// ---------------------------------------------------------------------------
// hl_lse: wave-per-row over all three matrices. 96 blocks x 8 waves = 768 rows.
// lane holds cols lane*4..+3 summed over the 8 K-partials; butterfly reduce;
// one atomicAdd per row. cm 0: local (w=0.4/256), cm 1: v2t, cm 2: t2v.
// ---------------------------------------------------------------------------
__global__ __launch_bounds__(512) void hl_lse(
    const float* __restrict__ cparts, float* __restrict__ out)
{
    const int rr   = (blockIdx.x << 3) + (threadIdx.x >> 6);  // 0..767
    const int cm   = rr >> 8;
    const int row  = rr & 255;
    const int lane = threadIdx.x & 63;
    const float w  = (cm == 0) ? (0.4f / 256.0f) : (0.3f / 256.0f);

    float4 x = make_float4(0.f, 0.f, 0.f, 0.f);
    const float* base = cparts + (size_t)cm * 65536 + (size_t)row * 256 + (lane << 2);
#pragma unroll
    for (int p = 0; p < 8; ++p) {
        float4 v = *(const float4*)(base + (size_t)p * 3 * 65536);
        x.x += v.x; x.y += v.y; x.z += v.z; x.w += v.w;
    }
    float m = fmaxf(fmaxf(x.x, x.y), fmaxf(x.z, x.w));
#pragma unroll
    for (int off = 32; off > 0; off >>= 1)
        m = fmaxf(m, __shfl_xor(m, off, 64));
    float e = expf(x.x - m) + expf(x.y - m) + expf(x.z - m) + expf(x.w - m);
#pragma unroll
    for (int off = 32; off > 0; off >>= 1)
        e += __shfl_xor(e, off, 64);
    if (lane == (row >> 2)) {
        float lse = m + logf(e);
        float xd = (row & 2) ? ((row & 1) ? x.w : x.z)
                             : ((row & 1) ? x.y : x.x);
        atomicAdd(out, w * (lse - xd));
    }
}

extern "C" void kernel_launch(void* const* d_in, const int* in_sizes, int n_in,
                              void* d_out, int out_size, void* d_ws, size_t ws_size,
                              hipStream_t stream)
{
    const float* vg   = (const float*)d_in[0];  // [256,768]
    const float* tg   = (const float*)d_in[1];  // [256,768]
    const float* vl   = (const float*)d_in[2];  // [256,16,768]
    const float* tl   = (const float*)d_in[3];  // [256,32,768]
    const float* temp = (const float*)d_in[4];  // [1]
    float* out = (float*)d_out;

    float* vw     = (float*)d_ws;                   // [256,768]
    float* tbw    = vw + (size_t)BB * DD;           // [256,768]
    float* cparts = tbw + (size_t)BB * DD;          // [8][3][256][256]

    hl_stage1<<<dim3(BB),  dim3(512), 0, stream>>>(vl, tl, temp, vw, tbw,
                                                   out, out_size);
    hl_gemm  <<<dim3(256), dim3(256), 0, stream>>>(vg, tg, vw, tbw, temp, cparts);
    hl_lse   <<<dim3(96),  dim3(512), 0, stream>>>(cparts, out);
}

// Round 4
// 115.511 us; speedup vs baseline: 1.0872x; 1.0872x over previous
//
#include <hip/hip_runtime.h>
#include <cmath>

#define BB 256
#define TT 16
#define SS 32
#define DD 768
#define LROW 260   // LDS staging row stride (floats), 16B-aligned

// ---------------------------------------------------------------------------
// stage1: per batch row i (256 blocks x 512 threads = 8 waves/CU)
//   sim[t][s] = ls*<vl[i,t,:], tl[i,s,:]>; tw = softmax_t(max_s sim)
//   vw[i,:] = sum_t tw[t]*vl[i,t,:];  tb[i,:] = mean_s tl[i,s,:]
// thread: slice = tid&15 (d-offset), g = tid>>4: tg = g>>3 (4 t-rows),
//         sg = g&7 (4 s-rows); acc[4][4].
// vs baseline: LDS quad XOR-swizzle P(q) = q ^ ((q>>3)&7) on the staging
// tile. Without it, av reads hit 8/32 banks (4x serialization) and bv reads
// hit 8/32 banks (4x serialization): q = 4*slice+step has q%8 in {step,step+4}
// only. P spreads quads over all 8 quad-groups (2 words/bank for av = HW
// minimum; 8 words/bank for bv = HW minimum for 1KB). P is an involution per
// row; write side places quad q=tid&63 at P(q), read side fetches P(q).
// ---------------------------------------------------------------------------
__global__ __launch_bounds__(512) void hl_stage1(
    const float* __restrict__ vl, const float* __restrict__ tl,
    const float* __restrict__ temp,
    float* __restrict__ vw_ws, float* __restrict__ tb_ws)
{
    __shared__ float smem[12480];   // 48 x 260 staging; aliased as 512x17 transpose
    __shared__ float simb[512];
    __shared__ float rmax[16];
    __shared__ float twb[16];

    const int i   = blockIdx.x;
    const int tid = threadIdx.x;
    const float lsc = expf(temp[0]);

    const int slice = tid & 15;   // d sub-offset: 16 lanes x 16B
    const int g     = tid >> 4;   // 0..31
    const int tg    = g >> 3;     // 0..3  -> t rows tg*4..+4
    const int sg    = g & 7;      // 0..7  -> s rows sg*4..+4

    const float* vli = vl + (size_t)i * TT * DD;
    const float* tli = tl + (size_t)i * SS * DD;

    float acc[4][4];
#pragma unroll
    for (int a = 0; a < 4; ++a)
#pragma unroll
        for (int b = 0; b < 4; ++b) acc[a][b] = 0.f;

    for (int c = 0; c < 3; ++c) {
        const int d0 = c << 8;
        // stage vl chunk 16x256 (1024 float4, 2 per thread), coalesced global,
        // quad-swizzled LDS placement
#pragma unroll
        for (int k = 0; k < 2; ++k) {
            int f4 = tid + (k << 9);
            int r  = f4 >> 6;
            int q  = f4 & 63;                     // logical quad in row
            int pq = q ^ ((q >> 3) & 7);          // physical quad (swizzle)
            *(float4*)&smem[r * LROW + (pq << 2)] =
                *(const float4*)&vli[r * DD + d0 + (q << 2)];
        }
        // stage tl chunk 32x256 (2048 float4, 4 per thread)
#pragma unroll
        for (int k = 0; k < 4; ++k) {
            int f4 = tid + (k << 9);
            int r  = f4 >> 6;
            int q  = f4 & 63;
            int pq = q ^ ((q >> 3) & 7);
            *(float4*)&smem[(16 + r) * LROW + (pq << 2)] =
                *(const float4*)&tli[r * DD + d0 + (q << 2)];
        }
        __syncthreads();
#pragma unroll
        for (int step = 0; step < 4; ++step) {
            // logical quad q = 4*slice + step; (q>>3)&7 == slice>>1
            const int db = (((slice << 2) + step) ^ (slice >> 1)) << 2;
            float4 av[4], bv[4];
#pragma unroll
            for (int ti = 0; ti < 4; ++ti)
                av[ti] = *(const float4*)&smem[(tg * 4 + ti) * LROW + db];
#pragma unroll
            for (int sj = 0; sj < 4; ++sj)
                bv[sj] = *(const float4*)&smem[(16 + sg * 4 + sj) * LROW + db];
#pragma unroll
            for (int ti = 0; ti < 4; ++ti)
#pragma unroll
                for (int sj = 0; sj < 4; ++sj)
                    acc[ti][sj] += av[ti].x * bv[sj].x + av[ti].y * bv[sj].y
                                 + av[ti].z * bv[sj].z + av[ti].w * bv[sj].w;
        }
        __syncthreads();
    }

    // split-D transpose (alias staging region): [pair][slice], pad 17
#pragma unroll
    for (int ti = 0; ti < 4; ++ti)
#pragma unroll
        for (int sj = 0; sj < 4; ++sj) {
            int t = tg * 4 + ti, s = sg * 4 + sj;
            smem[(t * 32 + s) * 17 + slice] = acc[ti][sj];
        }
    __syncthreads();
    {   // pair `tid` reduce over 16 slices
        float ssum = 0.f;
#pragma unroll
        for (int k = 0; k < 16; ++k) ssum += smem[tid * 17 + k];
        simb[tid] = lsc * ssum;
    }
    __syncthreads();
    if (tid < 16) {               // rowmax over s (rotated to avoid bank clash)
        float m = -3.0e38f;
        for (int s = 0; s < 32; ++s)
            m = fmaxf(m, simb[tid * 32 + ((s + tid) & 31)]);
        rmax[tid] = m;
    }
    __syncthreads();
    if (tid == 0) {               // tw = softmax over 16 t values
        float M = -3.0e38f;
        for (int t = 0; t < 16; ++t) M = fmaxf(M, rmax[t]);
        float ssum = 0.f;
        for (int t = 0; t < 16; ++t) {
            float e = expf(rmax[t] - M);
            twb[t] = e;
            ssum += e;
        }
        float inv = 1.0f / ssum;
        for (int t = 0; t < 16; ++t) twb[t] *= inv;
    }
    __syncthreads();

    // vw / tb tails: coalesced, L2-hot re-read
    for (int d = tid; d < DD; d += 512) {
        float vwv = 0.f;
#pragma unroll
        for (int t = 0; t < 16; ++t) vwv += twb[t] * vli[t * DD + d];
        vw_ws[(size_t)i * DD + d] = vwv;
        float tbv = 0.f;
#pragma unroll
        for (int s = 0; s < 32; ++s) tbv += tli[s * DD + d];
        tb_ws[(size_t)i * DD + d] = tbv * (1.0f / 32.0f);
    }
}

// ---------------------------------------------------------------------------
// hl_gemm: 256 blocks = mat(2) x ti(4) x tj(4) x p(8 K-splits of 96)
//   mat 0: G = ls*vg@tg^T  -> cparts[p][1] and transposed into cparts[p][2]
//   mat 1: L = ls*vw@tb^T  -> cparts[p][0]
// 64x64 tile, LDS-staged (As/Bs k-major), 4x4 register tile per thread.
// (LDS read audit: As 4 distinct quads broadcast; Bs 16 quads = 2 words/bank
//  = HW minimum. No swizzle needed.)
// ---------------------------------------------------------------------------
__global__ __launch_bounds__(256) void hl_gemm(
    const float* __restrict__ vg, const float* __restrict__ tg,
    const float* __restrict__ vw, const float* __restrict__ tb,
    const float* __restrict__ temp, float* __restrict__ cparts)
{
    __shared__ float As[16][68];
    __shared__ float Bs[16][68];
    __shared__ float Tb[64][68];

    const int b   = blockIdx.x;
    const int p   = b & 7;
    const int tj  = (b >> 3) & 3;
    const int ti  = (b >> 5) & 3;
    const int mat = b >> 7;
    const int tid = threadIdx.x;
    const float lsc = expf(temp[0]);

    const float* A  = mat ? vw : vg;
    const float* Bm = mat ? tb : tg;
    const int i0 = ti * 64, j0 = tj * 64, kb0 = p * 96;

    const int srow = tid >> 2, skq = tid & 3;   // staging: row, k-quad
    const int tr = tid >> 4, tc = tid & 15;     // compute: 4 rows, 4 cols each

    float acc[4][4];
#pragma unroll
    for (int r = 0; r < 4; ++r)
#pragma unroll
        for (int cc = 0; cc < 4; ++cc) acc[r][cc] = 0.f;

    for (int ch = 0; ch < 6; ++ch) {
        const int kb = kb0 + ch * 16;
        float4 a4 = *(const float4*)&A [(size_t)(i0 + srow) * DD + kb + skq * 4];
        float4 b4 = *(const float4*)&Bm[(size_t)(j0 + srow) * DD + kb + skq * 4];
        __syncthreads();
        As[skq * 4 + 0][srow] = a4.x; As[skq * 4 + 1][srow] = a4.y;
        As[skq * 4 + 2][srow] = a4.z; As[skq * 4 + 3][srow] = a4.w;
        Bs[skq * 4 + 0][srow] = b4.x; Bs[skq * 4 + 1][srow] = b4.y;
        Bs[skq * 4 + 2][srow] = b4.z; Bs[skq * 4 + 3][srow] = b4.w;
        __syncthreads();
#pragma unroll
        for (int k = 0; k < 16; ++k) {
            float4 av = *(const float4*)&As[k][tr * 4];
            float4 bv = *(const float4*)&Bs[k][tc * 4];
            float ar[4] = {av.x, av.y, av.z, av.w};
            float br[4] = {bv.x, bv.y, bv.z, bv.w};
#pragma unroll
            for (int r = 0; r < 4; ++r)
#pragma unroll
                for (int cc = 0; cc < 4; ++cc)
                    acc[r][cc] += ar[r] * br[cc];
        }
    }

    const int cm = mat ? 0 : 1;
    float* Cp = cparts + ((size_t)p * 3 + cm) * 65536;
#pragma unroll
    for (int r = 0; r < 4; ++r) {
        float4 v = {acc[r][0] * lsc, acc[r][1] * lsc, acc[r][2] * lsc, acc[r][3] * lsc};
        *(float4*)&Cp[(size_t)(i0 + tr * 4 + r) * 256 + j0 + tc * 4] = v;
    }
    if (mat == 0) {   // also write G^T for the t2v column-LSE
        __syncthreads();
#pragma unroll
        for (int r = 0; r < 4; ++r)
#pragma unroll
            for (int cc = 0; cc < 4; ++cc)
                Tb[tc * 4 + cc][tr * 4 + r] = acc[r][cc] * lsc;
        __syncthreads();
        float* Ct = cparts + ((size_t)p * 3 + 2) * 65536;
#pragma unroll
        for (int r = 0; r < 4; ++r) {
            float4 v = *(const float4*)&Tb[tr * 4 + r][tc * 4];
            *(float4*)&Ct[(size_t)(j0 + tr * 4 + r) * 256 + i0 + tc * 4] = v;
        }
    }
}

// ---------------------------------------------------------------------------
// hl_lse: 768 blocks = cm(3) x row(256). Sum 8 K-partials, block LSE,
// loss_row = lse - x[row]; weighted atomicAdd into out.
//   cm 0: local rows (w=0.4/256), cm 1: G rows = v2t, cm 2: G^T rows = t2v
// ---------------------------------------------------------------------------
__global__ __launch_bounds__(256) void hl_lse(
    const float* __restrict__ cparts, float* __restrict__ out)
{
    __shared__ float xs[256];
    __shared__ float wred[4];
    __shared__ float bcast;

    const int b   = blockIdx.x;
    const int cm  = b >> 8;
    const int row = b & 255;
    const int tid = threadIdx.x;

    float x = 0.f;
#pragma unroll
    for (int p = 0; p < 8; ++p)
        x += cparts[((size_t)p * 3 + cm) * 65536 + (size_t)row * 256 + tid];
    xs[tid] = x;

    float m = x;
#pragma unroll
    for (int off = 32; off > 0; off >>= 1)
        m = fmaxf(m, __shfl_down(m, off, 64));
    if ((tid & 63) == 0) wred[tid >> 6] = m;
    __syncthreads();
    if (tid == 0)
        bcast = fmaxf(fmaxf(wred[0], wred[1]), fmaxf(wred[2], wred[3]));
    __syncthreads();
    float M = bcast;
    float e = expf(x - M);
#pragma unroll
    for (int off = 32; off > 0; off >>= 1)
        e += __shfl_down(e, off, 64);
    if ((tid & 63) == 0) wred[tid >> 6] = e;
    __syncthreads();
    if (tid == 0) {
        float Stot = wred[0] + wred[1] + wred[2] + wred[3];
        float lse  = M + logf(Stot);
        float w    = (cm == 0) ? (0.4f / 256.0f) : (0.3f / 256.0f);
        atomicAdd(out, w * (lse - xs[row]));
    }
}

extern "C" void kernel_launch(void* const* d_in, const int* in_sizes, int n_in,
                              void* d_out, int out_size, void* d_ws, size_t ws_size,
                              hipStream_t stream)
{
    const float* vg   = (const float*)d_in[0];  // [256,768]
    const float* tg   = (const float*)d_in[1];  // [256,768]
    const float* vl   = (const float*)d_in[2];  // [256,16,768]
    const float* tl   = (const float*)d_in[3];  // [256,32,768]
    const float* temp = (const float*)d_in[4];  // [1]
    float* out = (float*)d_out;

    float* vw     = (float*)d_ws;                   // [256,768]
    float* tb     = vw + (size_t)BB * DD;           // [256,768]
    float* cparts = tb + (size_t)BB * DD;           // [8][3][256][256]

    hipMemsetAsync(out, 0, sizeof(float) * out_size, stream);
    hl_stage1<<<dim3(BB),  dim3(512), 0, stream>>>(vl, tl, temp, vw, tb);
    hl_gemm  <<<dim3(256), dim3(256), 0, stream>>>(vg, tg, vw, tb, temp, cparts);
    hl_lse   <<<dim3(768), dim3(256), 0, stream>>>(cparts, out);
}